// Round 4
// baseline (2134.658 us; speedup 1.0000x reference)
//
#include <hip/hip_runtime.h>
#include <hip/hip_bf16.h>

constexpr int cB = 32, cN = 64, cL = 64, cT = 10, cD = 256, cH = 512, cH3 = 1536;
constexpr int cBN = cB * cN;   // 2048
constexpr int cNP1 = cN + 1;   // 65: hidden tape, slot 0 = h0, slot n+1 = hs[:,n,:]

// x[bn][d] = sum_l emb[sents[bn][l]][d]   (one thread per output element)
__global__ void k_embed_x(const int* __restrict__ sents, const float* __restrict__ emb,
                          float* __restrict__ x) {
  int i = blockIdx.x * blockDim.x + threadIdx.x;  // BN*D
  int bn = i >> 8, d = i & 255;
  const int* s = sents + bn * cL;
  float acc = 0.f;
  for (int l = 0; l < cL; ++l) acc += emb[(long)s[l] * cD + d];
  x[i] = acc;
}

// tsum[b][d] = sum_t emb[titles[b][0][t]][d]
__global__ void k_title(const int* __restrict__ titles, const float* __restrict__ emb,
                        float* __restrict__ tsum) {
  int i = blockIdx.x * blockDim.x + threadIdx.x;  // B*D
  int b = i >> 8, d = i & 255;
  const int* tt = titles + b * cN * cT;           // titles[b][0][*]
  float acc = 0.f;
  for (int l = 0; l < cT; ++l) acc += emb[(long)tt[l] * cD + d];
  tsum[i] = acc;
}

// h0 = tsum @ Wt + bt  -> hse slot 0
__global__ void k_h0(const float* __restrict__ tsum, const float* __restrict__ Wt,
                     const float* __restrict__ bt, float* __restrict__ hse) {
  int i = blockIdx.x * blockDim.x + threadIdx.x;  // B*H
  int b = i >> 9, hh = i & 511;
  const float* ts = tsum + b * cD;
  float acc = bt[hh];
  for (int k = 0; k < cD; ++k) acc += ts[k] * Wt[k * cH + hh];
  hse[(b * cNP1) * cH + hh] = acc;
}

// gi[bn][c] = x[bn] . W_ih[:,c] + b_ih[c]
__global__ void k_gi(const float* __restrict__ x, const float* __restrict__ W_ih,
                     const float* __restrict__ b_ih, float* __restrict__ gi) {
  int bn = blockIdx.y;
  int c = blockIdx.x * blockDim.x + threadIdx.x;  // 0..1535
  const float* xr = x + bn * cD;
  float acc = b_ih[c];
  for (int k = 0; k < cD; ++k) acc += xr[k] * W_ih[k * cH3 + c];
  gi[bn * cH3 + c] = acc;
}

// one GRU step, one thread per (b, hh)
__global__ void k_gru_step(const float* __restrict__ gi, const float* __restrict__ W_hh,
                           const float* __restrict__ b_hh, float* __restrict__ hse, int step) {
  int i = blockIdx.x * blockDim.x + threadIdx.x;  // B*H
  int b = i >> 9, hh = i & 511;
  const float* h = hse + (b * cNP1 + step) * cH;
  float ar = b_hh[hh], az = b_hh[hh + cH], an = b_hh[hh + 2 * cH];
  for (int k = 0; k < cH; ++k) {
    float hv = h[k];
    const float* w = W_hh + k * cH3;
    ar += hv * w[hh];
    az += hv * w[hh + cH];
    an += hv * w[hh + 2 * cH];
  }
  const float* g = gi + (b * cN + step) * cH3;
  float ir = g[hh], iz = g[hh + cH], in_ = g[hh + 2 * cH];
  float r = 1.f / (1.f + expf(-(ir + ar)));
  float z = 1.f / (1.f + expf(-(iz + az)));
  float n = tanhf(in_ + r * an);
  hse[(b * cNP1 + step + 1) * cH + hh] = (1.f - z) * n + z * h[hh];
}

// q[bn][hh] = hs[bn] . W_att_in[:,hh]
__global__ void k_q(const float* __restrict__ hse, const float* __restrict__ W,
                    float* __restrict__ q) {
  int i = blockIdx.x * blockDim.x + threadIdx.x;  // BN*H
  int bn = i >> 9, hh = i & 511;
  int b = bn >> 6, n = bn & 63;
  const float* hr = hse + (b * cNP1 + 1 + n) * cH;
  float acc = 0.f;
  for (int k = 0; k < cH; ++k) acc += hr[k] * W[k * cH + hh];
  q[i] = acc;
}

// aw[bn][k] = softmax_k( q[bn] . hs[b,k]  masked k<=n )   (64 threads = 1 wave)
__global__ void k_scores(const float* __restrict__ q, const float* __restrict__ hse,
                         float* __restrict__ aw) {
  int bn = blockIdx.x;
  int b = bn >> 6, n = bn & 63;
  int t = threadIdx.x;  // key index
  const float* qr = q + bn * cH;
  const float* hr = hse + (b * cNP1 + 1 + t) * cH;
  float sc = 0.f;
  for (int j = 0; j < cH; ++j) sc += qr[j] * hr[j];
  if (t > n) sc = -1e30f;  // ref adds log(1e-45) ~ -103.6 -> exp underflow to 0
  float m = sc;
  for (int off = 32; off; off >>= 1) m = fmaxf(m, __shfl_xor(m, off));
  float e = expf(sc - m);
  float s = e;
  for (int off = 32; off; off >>= 1) s += __shfl_xor(s, off);
  aw[bn * cN + t] = e / s;
}

// c[bn][hh] = sum_k aw[bn][k] * hs[b,k][hh]
__global__ void k_ctx(const float* __restrict__ aw, const float* __restrict__ hse,
                      float* __restrict__ c) {
  int i = blockIdx.x * blockDim.x + threadIdx.x;  // BN*H
  int bn = i >> 9, hh = i & 511;
  int b = bn >> 6;
  const float* a = aw + bn * cN;
  float acc = 0.f;
  for (int k = 0; k < cN; ++k) acc += a[k] * hse[(b * cNP1 + 1 + k) * cH + hh];
  c[i] = acc;
}

// out[bn][hh] = tanh( [c[bn], hs[bn]] . W_att_out[:,hh] + b[hh] )   -- f32 output
__global__ void k_out(const float* __restrict__ c, const float* __restrict__ hse,
                      const float* __restrict__ W, const float* __restrict__ bias,
                      float* __restrict__ out) {
  int i = blockIdx.x * blockDim.x + threadIdx.x;  // BN*H
  int bn = i >> 9, hh = i & 511;
  int b = bn >> 6, n = bn & 63;
  const float* cr = c + bn * cH;
  const float* hr = hse + (b * cNP1 + 1 + n) * cH;
  float acc = bias[hh];
  for (int k = 0; k < cH; ++k) acc += cr[k] * W[k * cH + hh];
  for (int k = 0; k < cH; ++k) acc += hr[k] * W[(cH + k) * cH + hh];
  out[i] = tanhf(acc);
}

extern "C" void kernel_launch(void* const* d_in, const int* in_sizes, int n_in,
                              void* d_out, int out_size, void* d_ws, size_t ws_size,
                              hipStream_t stream) {
  const int* sents = (const int*)d_in[0];
  const int* titles = (const int*)d_in[1];
  const float* emb = (const float*)d_in[2];
  const float* Wt = (const float*)d_in[3];
  const float* bt = (const float*)d_in[4];
  const float* W_ih = (const float*)d_in[5];
  const float* W_hh = (const float*)d_in[6];
  const float* b_ih = (const float*)d_in[7];
  const float* b_hh = (const float*)d_in[8];
  const float* W_att_in = (const float*)d_in[9];
  const float* W_att_out = (const float*)d_in[10];
  const float* b_att_out = (const float*)d_in[11];
  float* out = (float*)d_out;

  // linear ws layout (floats), no aliasing: total ~27.9 MB
  float* ws = (float*)d_ws;
  float* x = ws;                                   // BN*D
  float* tsum = x + (long)cBN * cD;                // B*D
  float* gi = tsum + (long)cB * cD;                // BN*3H
  float* hse = gi + (long)cBN * cH3;               // B*65*H
  float* q = hse + (long)cB * cNP1 * cH;           // BN*H
  float* aw = q + (long)cBN * cH;                  // BN*N
  float* c = aw + (long)cBN * cN;                  // BN*H

  k_embed_x<<<(cBN * cD) / 256, 256, 0, stream>>>(sents, emb, x);
  k_title<<<(cB * cD) / 256, 256, 0, stream>>>(titles, emb, tsum);
  k_h0<<<(cB * cH) / 256, 256, 0, stream>>>(tsum, Wt, bt, hse);
  k_gi<<<dim3(cH3 / 256, cBN), 256, 0, stream>>>(x, W_ih, b_ih, gi);
  for (int step = 0; step < cN; ++step)
    k_gru_step<<<(cB * cH) / 256, 256, 0, stream>>>(gi, W_hh, b_hh, hse, step);
  k_q<<<(cBN * cH) / 256, 256, 0, stream>>>(hse, W_att_in, q);
  k_scores<<<cBN, 64, 0, stream>>>(q, hse, aw);
  k_ctx<<<(cBN * cH) / 256, 256, 0, stream>>>(aw, hse, c);
  k_out<<<(cBN * cH) / 256, 256, 0, stream>>>(c, hse, W_att_out, b_att_out, out);
}

// Round 5
// 1287.006 us; speedup vs baseline: 1.6586x; 1.6586x over previous
//
#include <hip/hip_runtime.h>
#include <hip/hip_bf16.h>

constexpr int cB = 32, cN = 64, cL = 64, cT = 10, cD = 256, cH = 512, cH3 = 1536;
constexpr int cBN = cB * cN;   // 2048
constexpr int cNP1 = cN + 1;   // 65: hidden tape, slot 0 = h0, slot n+1 = hs[:,n,:]

// ---------------- x[bn][d] = sum_l emb[sents[bn][l]][d] ----------------
__global__ void k_embed_x(const int* __restrict__ sents, const float* __restrict__ emb,
                          float* __restrict__ x) {
  __shared__ int idx[cL];
  int bn = blockIdx.x, t = threadIdx.x;
  if (t < cL) idx[t] = sents[bn * cL + t];
  __syncthreads();
  float acc = 0.f;
#pragma unroll 8
  for (int l = 0; l < cL; ++l) acc += emb[(long)idx[l] * cD + t];
  x[bn * cD + t] = acc;
}

// ---------------- tsum[b][d] = sum_t emb[titles[b][0][t]][d] ----------------
__global__ void k_title(const int* __restrict__ titles, const float* __restrict__ emb,
                        float* __restrict__ tsum) {
  __shared__ int idx[cT];
  int b = blockIdx.x, t = threadIdx.x;
  if (t < cT) idx[t] = titles[b * cN * cT + t];
  __syncthreads();
  float acc = 0.f;
#pragma unroll
  for (int i = 0; i < cT; ++i) acc += emb[(long)idx[i] * cD + t];
  tsum[b * cD + t] = acc;
}

// ---------------- h0 = tsum @ Wt + bt -> hse slot 0 ----------------
__global__ void k_h0(const float* __restrict__ tsum, const float* __restrict__ Wt,
                     const float* __restrict__ bt, float* __restrict__ hse) {
  int i = blockIdx.x * blockDim.x + threadIdx.x;  // B*H
  int b = i >> 9, hh = i & (cH - 1);
  const float* ts = tsum + b * cD;
  float acc = bt[hh];
  for (int k = 0; k < cD; ++k) acc += ts[k] * Wt[(long)k * cH + hh];
  hse[(long)b * cNP1 * cH + hh] = acc;
}

// ---------------- GI = X @ W_ih + b_ih  (M-tile 8) ----------------
__global__ void k_gi(const float* __restrict__ x, const float* __restrict__ W_ih,
                     const float* __restrict__ b_ih, float* __restrict__ gi) {
  __shared__ float xs[8][cD];
  int row0 = blockIdx.x * 8;
  int t = threadIdx.x;
#pragma unroll
  for (int m = 0; m < 8; ++m) xs[m][t] = x[(long)(row0 + m) * cD + t];
  __syncthreads();
  float acc[8][6];
#pragma unroll
  for (int m = 0; m < 8; ++m)
#pragma unroll
    for (int j = 0; j < 6; ++j) acc[m][j] = 0.f;
  for (int k = 0; k < cD; ++k) {
    float w[6];
    const float* wp = W_ih + (long)k * cH3 + t;
#pragma unroll
    for (int j = 0; j < 6; ++j) w[j] = wp[j * 256];
#pragma unroll
    for (int m = 0; m < 8; ++m) {
      float xv = xs[m][k];
#pragma unroll
      for (int j = 0; j < 6; ++j) acc[m][j] += xv * w[j];
    }
  }
#pragma unroll
  for (int m = 0; m < 8; ++m)
#pragma unroll
    for (int j = 0; j < 6; ++j)
      gi[(long)(row0 + m) * cH3 + t + j * 256] = acc[m][j] + b_ih[t + j * 256];
}

// ---------------- one GRU step ----------------
// grid 128 = (batch-group 0..7)*16 + (col-group g 0..15); block 256
// thread: hh-pair (t&15), batch-lane (t>>4)&3, k-part t>>6 (4 x 128)
__global__ void k_gru_step(const float* __restrict__ gi, const float* __restrict__ W_hh,
                           const float* __restrict__ b_hh, float* __restrict__ hse, int step) {
  __shared__ float hsm[4][cH + 4];
  __shared__ float part[256][7];
  int g = blockIdx.x & 15;
  int b0 = (blockIdx.x >> 4) * 4;
  int t = threadIdx.x;
#pragma unroll
  for (int m = 0; m < 4; ++m) {
    const float* r = hse + ((long)(b0 + m) * cNP1 + step) * cH;
    hsm[m][t] = r[t];
    hsm[m][t + 256] = r[t + 256];
  }
  __syncthreads();
  int hh2 = t & 15;
  int bl = (t >> 4) & 3;
  int p = t >> 6;
  int colr = g * 32 + hh2 * 2;
  float a[6] = {0, 0, 0, 0, 0, 0};
  const float* hrow = &hsm[bl][0];
  int k0 = p * 128;
#pragma unroll 8
  for (int k = k0; k < k0 + 128; ++k) {
    float hv = hrow[k];
    const float* wp = W_hh + (long)k * cH3 + colr;
    float2 wr = *(const float2*)(wp);
    float2 wz = *(const float2*)(wp + cH);
    float2 wn = *(const float2*)(wp + 2 * cH);
    a[0] += hv * wr.x;
    a[1] += hv * wr.y;
    a[2] += hv * wz.x;
    a[3] += hv * wz.y;
    a[4] += hv * wn.x;
    a[5] += hv * wn.y;
  }
#pragma unroll
  for (int j = 0; j < 6; ++j) part[t][j] = a[j];
  __syncthreads();
  if (t < 64) {
    int hh2f = t & 15, blf = t >> 4;
    float r0[6];
#pragma unroll
    for (int j = 0; j < 6; ++j)
      r0[j] = part[t][j] + part[t + 64][j] + part[t + 128][j] + part[t + 192][j];
    int b = b0 + blf;
    long girow = ((long)b * cN + step) * cH3;
    long orow = ((long)b * cNP1 + step + 1) * cH;
#pragma unroll
    for (int j = 0; j < 2; ++j) {
      int hh = g * 32 + hh2f * 2 + j;
      float ar = r0[j] + b_hh[hh];
      float az = r0[2 + j] + b_hh[hh + cH];
      float an = r0[4 + j] + b_hh[hh + 2 * cH];
      float ir = gi[girow + hh];
      float iz = gi[girow + hh + cH];
      float in_ = gi[girow + hh + 2 * cH];
      float rr = 1.f / (1.f + __expf(-(ir + ar)));
      float zz = 1.f / (1.f + __expf(-(iz + az)));
      float nn = tanhf(in_ + rr * an);
      hse[orow + hh] = (1.f - zz) * nn + zz * hsm[blf][hh];
    }
  }
}

// ---------------- q = hs @ W_att_in  (M-tile 8) ----------------
__global__ void k_q(const float* __restrict__ hse, const float* __restrict__ W,
                    float* __restrict__ q) {
  __shared__ float s[8][cH];
  int row0 = blockIdx.x * 8;
  int t = threadIdx.x;
#pragma unroll
  for (int m = 0; m < 8; ++m) {
    int bn = row0 + m;
    int b = bn >> 6, n = bn & 63;
    const float* r = hse + ((long)b * cNP1 + 1 + n) * cH;
    s[m][t] = r[t];
    s[m][t + 256] = r[t + 256];
  }
  __syncthreads();
  float a0[8], a1[8];
#pragma unroll
  for (int m = 0; m < 8; ++m) { a0[m] = 0.f; a1[m] = 0.f; }
  for (int k = 0; k < cH; ++k) {
    float w0 = W[(long)k * cH + t];
    float w1 = W[(long)k * cH + t + 256];
#pragma unroll
    for (int m = 0; m < 8; ++m) {
      a0[m] += s[m][k] * w0;
      a1[m] += s[m][k] * w1;
    }
  }
#pragma unroll
  for (int m = 0; m < 8; ++m) {
    q[(long)(row0 + m) * cH + t] = a0[m];
    q[(long)(row0 + m) * cH + t + 256] = a1[m];
  }
}

// ---------------- causal attention: scores + softmax + context ----------------
__global__ void k_attn(const float* __restrict__ q, const float* __restrict__ hse,
                       float* __restrict__ c) {
  __shared__ float qs[cH];
  __shared__ float part[256];
  __shared__ float aw[cN];
  int bn = blockIdx.x;
  int b = bn >> 6, n = bn & 63;
  int t = threadIdx.x;
  qs[t] = q[(long)bn * cH + t];
  qs[t + 256] = q[(long)bn * cH + t + 256];
  __syncthreads();
  int k = t & 63;
  int p = t >> 6;  // 4 partials per key
  const float* hrow = hse + ((long)b * cNP1 + 1 + k) * cH + p * 128;
  float s = 0.f;
#pragma unroll 8
  for (int j = 0; j < 128; ++j) s += qs[p * 128 + j] * hrow[j];
  part[t] = s;
  __syncthreads();
  if (t < 64) {
    float sc = part[t] + part[t + 64] + part[t + 128] + part[t + 192];
    if (t > n) sc = -1e30f;  // ref adds log(1e-45) ~ -103.6 -> exp underflows to 0
    float m = sc;
#pragma unroll
    for (int off = 32; off; off >>= 1) m = fmaxf(m, __shfl_xor(m, off));
    float e = __expf(sc - m);
    float sum = e;
#pragma unroll
    for (int off = 32; off; off >>= 1) sum += __shfl_xor(sum, off);
    aw[t] = e / sum;
  }
  __syncthreads();
  float c0 = 0.f, c1 = 0.f;
  for (int kk = 0; kk < cN; ++kk) {
    float a = aw[kk];
    const float* hr = hse + ((long)b * cNP1 + 1 + kk) * cH;
    c0 += a * hr[t];
    c1 += a * hr[t + 256];
  }
  c[(long)bn * cH + t] = c0;
  c[(long)bn * cH + t + 256] = c1;
}

// ---------------- out = tanh(concat(c,hs) @ W_att_out + b)  (M-tile 8, f32 out) ----------------
__global__ void k_out(const float* __restrict__ c, const float* __restrict__ hse,
                      const float* __restrict__ W, const float* __restrict__ bias,
                      float* __restrict__ out) {
  __shared__ float s[8][2 * cH];
  int row0 = blockIdx.x * 8;
  int t = threadIdx.x;
#pragma unroll
  for (int m = 0; m < 8; ++m) {
    int bn = row0 + m;
    int b = bn >> 6, n = bn & 63;
    const float* cr = c + (long)bn * cH;
    const float* hr = hse + ((long)b * cNP1 + 1 + n) * cH;
    s[m][t] = cr[t];
    s[m][t + 256] = cr[t + 256];
    s[m][cH + t] = hr[t];
    s[m][cH + t + 256] = hr[t + 256];
  }
  __syncthreads();
  float a0[8], a1[8];
#pragma unroll
  for (int m = 0; m < 8; ++m) { a0[m] = 0.f; a1[m] = 0.f; }
  for (int k = 0; k < 2 * cH; ++k) {
    float w0 = W[(long)k * cH + t];
    float w1 = W[(long)k * cH + t + 256];
#pragma unroll
    for (int m = 0; m < 8; ++m) {
      a0[m] += s[m][k] * w0;
      a1[m] += s[m][k] * w1;
    }
  }
  float b0 = bias[t], b1 = bias[t + 256];
#pragma unroll
  for (int m = 0; m < 8; ++m) {
    out[(long)(row0 + m) * cH + t] = tanhf(a0[m] + b0);
    out[(long)(row0 + m) * cH + t + 256] = tanhf(a1[m] + b1);
  }
}

extern "C" void kernel_launch(void* const* d_in, const int* in_sizes, int n_in,
                              void* d_out, int out_size, void* d_ws, size_t ws_size,
                              hipStream_t stream) {
  const int* sents = (const int*)d_in[0];
  const int* titles = (const int*)d_in[1];
  const float* emb = (const float*)d_in[2];
  const float* Wt = (const float*)d_in[3];
  const float* bt = (const float*)d_in[4];
  const float* W_ih = (const float*)d_in[5];
  const float* W_hh = (const float*)d_in[6];
  const float* b_ih = (const float*)d_in[7];
  const float* b_hh = (const float*)d_in[8];
  const float* W_att_in = (const float*)d_in[9];
  const float* W_att_out = (const float*)d_in[10];
  const float* b_att_out = (const float*)d_in[11];
  float* out = (float*)d_out;

  // linear ws layout (floats), no aliasing: ~26.1 MB (ws >= 27.9 MB proven in round 4)
  float* ws = (float*)d_ws;
  float* x = ws;                                   // BN*D
  float* tsum = x + (long)cBN * cD;                // B*D
  float* gi = tsum + (long)cB * cD;                // BN*3H
  float* hse = gi + (long)cBN * cH3;               // B*65*H
  float* q = hse + (long)cB * cNP1 * cH;           // BN*H
  float* c = q + (long)cBN * cH;                   // BN*H

  k_embed_x<<<cBN, 256, 0, stream>>>(sents, emb, x);
  k_title<<<cB, 256, 0, stream>>>(titles, emb, tsum);
  k_h0<<<(cB * cH) / 256, 256, 0, stream>>>(tsum, Wt, bt, hse);
  k_gi<<<cBN / 8, 256, 0, stream>>>(x, W_ih, b_ih, gi);
  for (int step = 0; step < cN; ++step)
    k_gru_step<<<128, 256, 0, stream>>>(gi, W_hh, b_hh, hse, step);
  k_q<<<cBN / 8, 256, 0, stream>>>(hse, W_att_in, q);
  k_attn<<<cBN, 256, 0, stream>>>(q, hse, c);
  k_out<<<cBN / 8, 256, 0, stream>>>(c, hse, W_att_out, b_att_out, out);
}

// Round 6
// 1234.510 us; speedup vs baseline: 1.7292x; 1.0425x over previous
//
#include <hip/hip_runtime.h>
#include <hip/hip_bf16.h>

constexpr int cB = 32, cN = 64, cL = 64, cT = 10, cD = 256, cH = 512, cH3 = 1536;
constexpr int cBN = cB * cN;   // 2048
constexpr int cNP1 = cN + 1;   // 65: hidden tape, slot 0 = h0, slot n+1 = hs[:,n,:]

// ---------------- x[bn][d] = sum_l emb[sents[bn][l]][d] ----------------
__global__ void k_embed_x(const int* __restrict__ sents, const float* __restrict__ emb,
                          float* __restrict__ x) {
  __shared__ int idx[cL];
  int bn = blockIdx.x, t = threadIdx.x;
  if (t < cL) idx[t] = sents[bn * cL + t];
  __syncthreads();
  float acc = 0.f;
#pragma unroll 8
  for (int l = 0; l < cL; ++l) acc += emb[(long)idx[l] * cD + t];
  x[bn * cD + t] = acc;
}

// ---------------- tsum[b][d] = sum_t emb[titles[b][0][t]][d] ----------------
__global__ void k_title(const int* __restrict__ titles, const float* __restrict__ emb,
                        float* __restrict__ tsum) {
  __shared__ int idx[cT];
  int b = blockIdx.x, t = threadIdx.x;
  if (t < cT) idx[t] = titles[b * cN * cT + t];
  __syncthreads();
  float acc = 0.f;
#pragma unroll
  for (int i = 0; i < cT; ++i) acc += emb[(long)idx[i] * cD + t];
  tsum[b * cD + t] = acc;
}

// ---------------- h0 = tsum @ Wt + bt -> hse slot 0 ----------------
__global__ void k_h0(const float* __restrict__ tsum, const float* __restrict__ Wt,
                     const float* __restrict__ bt, float* __restrict__ hse) {
  int i = blockIdx.x * blockDim.x + threadIdx.x;  // B*H
  int b = i >> 9, hh = i & (cH - 1);
  const float* ts = tsum + b * cD;
  float acc = bt[hh];
  for (int k = 0; k < cD; ++k) acc += ts[k] * Wt[(long)k * cH + hh];
  hse[(long)b * cNP1 * cH + hh] = acc;
}

// ---------------- GI = X @ W_ih + b_ih ----------------
// grid (6 col-groups, 256 row-groups); block 256; 1 col/thread, 8 rows/block
__global__ void k_gi(const float* __restrict__ x, const float* __restrict__ W_ih,
                     const float* __restrict__ b_ih, float* __restrict__ gi) {
  __shared__ float s[8 * cD];                      // 8 KB
  int cg = blockIdx.x;
  int row0 = blockIdx.y * 8;
  int t = threadIdx.x;
  float4* s4 = (float4*)s;
  const float4* x4 = (const float4*)(x + (long)row0 * cD);
#pragma unroll
  for (int i = t; i < 8 * (cD / 4); i += 256) s4[i] = x4[i];  // rows contiguous
  __syncthreads();
  int col = cg * 256 + t;
  float acc[8] = {0, 0, 0, 0, 0, 0, 0, 0};
#pragma unroll 2
  for (int k4 = 0; k4 < cD / 4; ++k4) {
    float4 a[8];
#pragma unroll
    for (int m = 0; m < 8; ++m) a[m] = s4[m * (cD / 4) + k4];
    const float* wp = W_ih + (long)(k4 * 4) * cH3 + col;
    float w0 = wp[0], w1 = wp[cH3], w2 = wp[2 * cH3], w3 = wp[3 * cH3];
#pragma unroll
    for (int m = 0; m < 8; ++m)
      acc[m] += a[m].x * w0 + a[m].y * w1 + a[m].z * w2 + a[m].w * w3;
  }
  float bb = b_ih[col];
#pragma unroll
  for (int m = 0; m < 8; ++m) gi[(long)(row0 + m) * cH3 + col] = acc[m] + bb;
}

// ---------------- one GRU step ----------------
// grid 128 = (batch-group 0..7)*16 + (col-group g 0..15); block 256
__global__ void k_gru_step(const float* __restrict__ gi, const float* __restrict__ W_hh,
                           const float* __restrict__ b_hh, float* __restrict__ hse, int step) {
  __shared__ float hsm[4][cH + 4];
  __shared__ float part[256][7];
  int g = blockIdx.x & 15;
  int b0 = (blockIdx.x >> 4) * 4;
  int t = threadIdx.x;
  // stage 4 hidden rows as float4 (rows of hsm are 16B-aligned: 516*4 = 2064 = 129*16)
#pragma unroll
  for (int i = t; i < 4 * 128; i += 256) {
    int m = i >> 7, k4 = i & 127;
    const float4* r4 = (const float4*)(hse + ((long)(b0 + m) * cNP1 + step) * cH);
    ((float4*)&hsm[m][0])[k4] = r4[k4];
  }
  __syncthreads();
  int hh2 = t & 15;
  int bl = (t >> 4) & 3;
  int p = t >> 6;
  int colr = g * 32 + hh2 * 2;
  float a[6] = {0, 0, 0, 0, 0, 0};
  const float* hrow = &hsm[bl][0];
  int k0 = p * 128;
#pragma unroll 8
  for (int k = k0; k < k0 + 128; ++k) {
    float hv = hrow[k];
    const float* wp = W_hh + (long)k * cH3 + colr;
    float2 wr = *(const float2*)(wp);
    float2 wz = *(const float2*)(wp + cH);
    float2 wn = *(const float2*)(wp + 2 * cH);
    a[0] += hv * wr.x;
    a[1] += hv * wr.y;
    a[2] += hv * wz.x;
    a[3] += hv * wz.y;
    a[4] += hv * wn.x;
    a[5] += hv * wn.y;
  }
#pragma unroll
  for (int j = 0; j < 6; ++j) part[t][j] = a[j];
  __syncthreads();
  if (t < 128) {  // 2 waves, 1 output each: (b_local, hh_local)
    int hh_local = t & 31, b_local = t >> 5;
    int hh2f = hh_local >> 1, c01 = hh_local & 1;
    int rbase = b_local * 16 + hh2f;
    float sr = 0.f, sz = 0.f, sn = 0.f;
#pragma unroll
    for (int pp = 0; pp < 4; ++pp) {
      int r = rbase + pp * 64;
      sr += part[r][c01];
      sz += part[r][2 + c01];
      sn += part[r][4 + c01];
    }
    int b = b0 + b_local;
    int hh = g * 32 + hh_local;
    long girow = ((long)b * cN + step) * cH3;
    float ar = sr + b_hh[hh];
    float az = sz + b_hh[hh + cH];
    float an = sn + b_hh[hh + 2 * cH];
    float ir = gi[girow + hh];
    float iz = gi[girow + hh + cH];
    float in_ = gi[girow + hh + 2 * cH];
    float rr = 1.f / (1.f + __expf(-(ir + ar)));
    float zz = 1.f / (1.f + __expf(-(iz + az)));
    float nn = tanhf(in_ + rr * an);
    hse[((long)b * cNP1 + step + 1) * cH + hh] = (1.f - zz) * nn + zz * hsm[b_local][hh];
  }
}

// ---------------- q = hs @ W_att_in ----------------
// grid (2 col-groups, 256 row-groups); block 256
__global__ void k_q(const float* __restrict__ hse, const float* __restrict__ W,
                    float* __restrict__ q) {
  __shared__ float s[8 * cH];                      // 16 KB
  int cg = blockIdx.x;
  int row0 = blockIdx.y * 8;
  int t = threadIdx.x;
  float4* s4 = (float4*)s;
#pragma unroll
  for (int i = t; i < 8 * 128; i += 256) {
    int m = i >> 7, k4 = i & 127;
    int bn = row0 + m;
    int b = bn >> 6, n = bn & 63;
    const float4* r4 = (const float4*)(hse + ((long)b * cNP1 + 1 + n) * cH);
    s4[m * 128 + k4] = r4[k4];
  }
  __syncthreads();
  int col = cg * 256 + t;
  float acc[8] = {0, 0, 0, 0, 0, 0, 0, 0};
#pragma unroll 2
  for (int k4 = 0; k4 < cH / 4; ++k4) {
    float4 a[8];
#pragma unroll
    for (int m = 0; m < 8; ++m) a[m] = s4[m * 128 + k4];
    const float* wp = W + (long)(k4 * 4) * cH + col;
    float w0 = wp[0], w1 = wp[cH], w2 = wp[2 * cH], w3 = wp[3 * cH];
#pragma unroll
    for (int m = 0; m < 8; ++m)
      acc[m] += a[m].x * w0 + a[m].y * w1 + a[m].z * w2 + a[m].w * w3;
  }
#pragma unroll
  for (int m = 0; m < 8; ++m) q[(long)(row0 + m) * cH + col] = acc[m];
}

// ---------------- causal attention: scores + softmax + context ----------------
__global__ void k_attn(const float* __restrict__ q, const float* __restrict__ hse,
                       float* __restrict__ c) {
  __shared__ float qs[cH];
  __shared__ float part[256];
  __shared__ float aw[cN];
  int bn = blockIdx.x;
  int b = bn >> 6, n = bn & 63;
  int t = threadIdx.x;
  qs[t] = q[(long)bn * cH + t];
  qs[t + 256] = q[(long)bn * cH + t + 256];
  __syncthreads();
  int k = t & 63;
  int p = t >> 6;  // 4 partials per key
  const float* hrow = hse + ((long)b * cNP1 + 1 + k) * cH + p * 128;
  float s = 0.f;
#pragma unroll 8
  for (int j = 0; j < 128; ++j) s += qs[p * 128 + j] * hrow[j];
  part[t] = s;
  __syncthreads();
  if (t < 64) {
    float sc = part[t] + part[t + 64] + part[t + 128] + part[t + 192];
    if (t > n) sc = -1e30f;  // ref adds log(1e-45) ~ -103.6 -> exp underflows to 0
    float m = sc;
#pragma unroll
    for (int off = 32; off; off >>= 1) m = fmaxf(m, __shfl_xor(m, off));
    float e = __expf(sc - m);
    float sum = e;
#pragma unroll
    for (int off = 32; off; off >>= 1) sum += __shfl_xor(sum, off);
    aw[t] = e / sum;
  }
  __syncthreads();
  float c0 = 0.f, c1 = 0.f;
  for (int kk = 0; kk < cN; ++kk) {
    float a = aw[kk];
    const float* hr = hse + ((long)b * cNP1 + 1 + kk) * cH;
    c0 += a * hr[t];
    c1 += a * hr[t + 256];
  }
  c[(long)bn * cH + t] = c0;
  c[(long)bn * cH + t + 256] = c1;
}

// ---------------- out = tanh(concat(c,hs) @ W_att_out + b) ----------------
// grid (2 col-groups, 256 row-groups); block 256
__global__ void k_out(const float* __restrict__ c, const float* __restrict__ hse,
                      const float* __restrict__ W, const float* __restrict__ bias,
                      float* __restrict__ out) {
  __shared__ float s[8 * 2 * cH];                  // 32 KB
  int cg = blockIdx.x;
  int row0 = blockIdx.y * 8;
  int t = threadIdx.x;
  float4* s4 = (float4*)s;
#pragma unroll
  for (int m = 0; m < 8; ++m) {
    int bn = row0 + m;
    int b = bn >> 6, n = bn & 63;
    const float4* cr = (const float4*)(c + (long)bn * cH);                      // 128 f4
    const float4* hr = (const float4*)(hse + ((long)b * cNP1 + 1 + n) * cH);    // 128 f4
    float4 v = (t < 128) ? cr[t] : hr[t - 128];
    s4[m * 256 + t] = v;
  }
  __syncthreads();
  int col = cg * 256 + t;
  float acc[8] = {0, 0, 0, 0, 0, 0, 0, 0};
#pragma unroll 2
  for (int k4 = 0; k4 < (2 * cH) / 4; ++k4) {
    float4 a[8];
#pragma unroll
    for (int m = 0; m < 8; ++m) a[m] = s4[m * 256 + k4];
    const float* wp = W + (long)(k4 * 4) * cH + col;
    float w0 = wp[0], w1 = wp[cH], w2 = wp[2 * cH], w3 = wp[3 * cH];
#pragma unroll
    for (int m = 0; m < 8; ++m)
      acc[m] += a[m].x * w0 + a[m].y * w1 + a[m].z * w2 + a[m].w * w3;
  }
  float bb = bias[col];
#pragma unroll
  for (int m = 0; m < 8; ++m) out[(long)(row0 + m) * cH + col] = tanhf(acc[m] + bb);
}

extern "C" void kernel_launch(void* const* d_in, const int* in_sizes, int n_in,
                              void* d_out, int out_size, void* d_ws, size_t ws_size,
                              hipStream_t stream) {
  const int* sents = (const int*)d_in[0];
  const int* titles = (const int*)d_in[1];
  const float* emb = (const float*)d_in[2];
  const float* Wt = (const float*)d_in[3];
  const float* bt = (const float*)d_in[4];
  const float* W_ih = (const float*)d_in[5];
  const float* W_hh = (const float*)d_in[6];
  const float* b_ih = (const float*)d_in[7];
  const float* b_hh = (const float*)d_in[8];
  const float* W_att_in = (const float*)d_in[9];
  const float* W_att_out = (const float*)d_in[10];
  const float* b_att_out = (const float*)d_in[11];
  float* out = (float*)d_out;

  float* ws = (float*)d_ws;
  float* x = ws;                                   // BN*D
  float* tsum = x + (long)cBN * cD;                // B*D
  float* gi = tsum + (long)cB * cD;                // BN*3H
  float* hse = gi + (long)cBN * cH3;               // B*65*H
  float* q = hse + (long)cB * cNP1 * cH;           // BN*H
  float* c = q + (long)cBN * cH;                   // BN*H

  k_embed_x<<<cBN, 256, 0, stream>>>(sents, emb, x);
  k_title<<<cB, 256, 0, stream>>>(titles, emb, tsum);
  k_h0<<<(cB * cH) / 256, 256, 0, stream>>>(tsum, Wt, bt, hse);
  k_gi<<<dim3(6, cBN / 8), 256, 0, stream>>>(x, W_ih, b_ih, gi);
  for (int step = 0; step < cN; ++step)
    k_gru_step<<<128, 256, 0, stream>>>(gi, W_hh, b_hh, hse, step);
  k_q<<<dim3(2, cBN / 8), 256, 0, stream>>>(hse, W_att_in, q);
  k_attn<<<cBN, 256, 0, stream>>>(q, hse, c);
  k_out<<<dim3(2, cBN / 8), 256, 0, stream>>>(c, hse, W_att_out, b_att_out, out);
}

// Round 7
// 638.448 us; speedup vs baseline: 3.3435x; 1.9336x over previous
//
#include <hip/hip_runtime.h>
#include <hip/hip_bf16.h>

constexpr int cB = 32, cN = 64, cL = 64, cT = 10, cD = 256, cH = 512, cH3 = 1536;
constexpr int cBN = cB * cN;   // 2048
constexpr int cNP1 = cN + 1;   // 65: hidden tape, slot 0 = h0, slot n+1 = hs[:,n,:]

// ---------------- x[bn][d] = sum_l emb[sents[bn][l]][d] ----------------
__global__ void k_embed_x(const int* __restrict__ sents, const float* __restrict__ emb,
                          float* __restrict__ x) {
  __shared__ int idx[cL];
  int bn = blockIdx.x, t = threadIdx.x;
  if (t < cL) idx[t] = sents[bn * cL + t];
  __syncthreads();
  float acc = 0.f;
#pragma unroll 8
  for (int l = 0; l < cL; ++l) acc += emb[(long)idx[l] * cD + t];
  x[bn * cD + t] = acc;
}

// ---------------- tsum[b][d] = sum_t emb[titles[b][0][t]][d] ----------------
__global__ void k_title(const int* __restrict__ titles, const float* __restrict__ emb,
                        float* __restrict__ tsum) {
  __shared__ int idx[cT];
  int b = blockIdx.x, t = threadIdx.x;
  if (t < cT) idx[t] = titles[b * cN * cT + t];
  __syncthreads();
  float acc = 0.f;
#pragma unroll
  for (int i = 0; i < cT; ++i) acc += emb[(long)idx[i] * cD + t];
  tsum[b * cD + t] = acc;
}

// ---------------- h0 = tsum @ Wt + bt -> hse slot 0 ----------------
__global__ void k_h0(const float* __restrict__ tsum, const float* __restrict__ Wt,
                     const float* __restrict__ bt, float* __restrict__ hse) {
  int i = blockIdx.x * blockDim.x + threadIdx.x;  // B*H
  int b = i >> 9, hh = i & (cH - 1);
  const float* ts = tsum + b * cD;
  float acc = bt[hh];
  for (int k = 0; k < cD; ++k) acc += ts[k] * Wt[(long)k * cH + hh];
  hse[(long)b * cNP1 * cH + hh] = acc;
}

// ---------------- GI = X @ W_ih + b_ih ----------------
// grid (6 col-groups, 256 row-groups); block 256; 1 col/thread, 8 rows/block
__global__ void k_gi(const float* __restrict__ x, const float* __restrict__ W_ih,
                     const float* __restrict__ b_ih, float* __restrict__ gi) {
  __shared__ float s[8 * cD];                      // 8 KB
  int cg = blockIdx.x;
  int row0 = blockIdx.y * 8;
  int t = threadIdx.x;
  float4* s4 = (float4*)s;
  const float4* x4 = (const float4*)(x + (long)row0 * cD);
#pragma unroll
  for (int i = t; i < 8 * (cD / 4); i += 256) s4[i] = x4[i];  // rows contiguous
  __syncthreads();
  int col = cg * 256 + t;
  float acc[8] = {0, 0, 0, 0, 0, 0, 0, 0};
#pragma unroll 2
  for (int k4 = 0; k4 < cD / 4; ++k4) {
    float4 a[8];
#pragma unroll
    for (int m = 0; m < 8; ++m) a[m] = s4[m * (cD / 4) + k4];
    const float* wp = W_ih + (long)(k4 * 4) * cH3 + col;
    float w0 = wp[0], w1 = wp[cH3], w2 = wp[2 * cH3], w3 = wp[3 * cH3];
#pragma unroll
    for (int m = 0; m < 8; ++m)
      acc[m] += a[m].x * w0 + a[m].y * w1 + a[m].z * w2 + a[m].w * w3;
  }
  float bb = b_ih[col];
#pragma unroll
  for (int m = 0; m < 8; ++m) gi[(long)(row0 + m) * cH3 + col] = acc[m] + bb;
}

// ---------------- one GRU step ----------------
// grid 512 = bg(16: 2 batches) x cg(32: 16 cols/gate); block 256
// thread t = kp*8 + b*4 + c4 : kp in [0,32) k-chunk 16, b in [0,2), c4 in [0,4) 4 cols
__global__ void k_gru_step(const float* __restrict__ gi, const float* __restrict__ W_hh,
                           const float* __restrict__ b_hh, float* __restrict__ hse, int step) {
  __shared__ float hsm[2][cH];
  __shared__ float part[256][13];   // stride 13: conflict-free partial writes
  int cg = blockIdx.x & 31;
  int bg = blockIdx.x >> 5;
  int t = threadIdx.x;
  {  // stage 2 hidden rows (4 KB): 256 threads x 1 float4
    int m = t >> 7, k4 = t & 127;
    const float4* r4 = (const float4*)(hse + ((long)(bg * 2 + m) * cNP1 + step) * cH);
    ((float4*)&hsm[m][0])[k4] = r4[k4];
  }
  __syncthreads();
  int c4 = t & 3, b = (t >> 2) & 1, kp = t >> 3;
  int col0 = cg * 16 + c4 * 4;
  float ar[4] = {0, 0, 0, 0}, az[4] = {0, 0, 0, 0}, an[4] = {0, 0, 0, 0};
  int k0 = kp * 16;
#pragma unroll
  for (int k = k0; k < k0 + 16; ++k) {
    float hv = hsm[b][k];
    const float* wp = W_hh + (long)k * cH3 + col0;
    float4 wr = *(const float4*)(wp);
    float4 wz = *(const float4*)(wp + cH);
    float4 wn = *(const float4*)(wp + 2 * cH);
    ar[0] += hv * wr.x; ar[1] += hv * wr.y; ar[2] += hv * wr.z; ar[3] += hv * wr.w;
    az[0] += hv * wz.x; az[1] += hv * wz.y; az[2] += hv * wz.z; az[3] += hv * wz.w;
    an[0] += hv * wn.x; an[1] += hv * wn.y; an[2] += hv * wn.z; an[3] += hv * wn.w;
  }
#pragma unroll
  for (int j = 0; j < 4; ++j) {
    part[t][j] = ar[j];
    part[t][4 + j] = az[j];
    part[t][8 + j] = an[j];
  }
  __syncthreads();
  if (t < 32) {  // 32 outputs: b_l in [0,2), cl in [0,16)
    int b_l = t >> 4, cl = t & 15;
    int c4f = cl >> 2, jf = cl & 3;
    float sr = 0.f, sz = 0.f, sn = 0.f;
#pragma unroll
    for (int p = 0; p < 32; ++p) {
      const float* pp = part[p * 8 + b_l * 4 + c4f];
      sr += pp[jf];
      sz += pp[4 + jf];
      sn += pp[8 + jf];
    }
    int bb = bg * 2 + b_l;
    int hh = cg * 16 + cl;
    long girow = ((long)bb * cN + step) * cH3;
    float R = sr + b_hh[hh];
    float Z = sz + b_hh[hh + cH];
    float Nn = sn + b_hh[hh + 2 * cH];
    float ir = gi[girow + hh];
    float iz = gi[girow + hh + cH];
    float in_ = gi[girow + hh + 2 * cH];
    float rr = 1.f / (1.f + __expf(-(ir + R)));
    float zz = 1.f / (1.f + __expf(-(iz + Z)));
    float nn = tanhf(in_ + rr * Nn);
    hse[((long)bb * cNP1 + step + 1) * cH + hh] = (1.f - zz) * nn + zz * hsm[b_l][hh];
  }
}

// ---------------- q = hs @ W_att_in ----------------
// grid (2 col-groups, 256 row-groups); block 256
__global__ void k_q(const float* __restrict__ hse, const float* __restrict__ W,
                    float* __restrict__ q) {
  __shared__ float s[8 * cH];                      // 16 KB
  int cg = blockIdx.x;
  int row0 = blockIdx.y * 8;
  int t = threadIdx.x;
  float4* s4 = (float4*)s;
#pragma unroll
  for (int i = t; i < 8 * 128; i += 256) {
    int m = i >> 7, k4 = i & 127;
    int bn = row0 + m;
    int b = bn >> 6, n = bn & 63;
    const float4* r4 = (const float4*)(hse + ((long)b * cNP1 + 1 + n) * cH);
    s4[m * 128 + k4] = r4[k4];
  }
  __syncthreads();
  int col = cg * 256 + t;
  float acc[8] = {0, 0, 0, 0, 0, 0, 0, 0};
#pragma unroll 2
  for (int k4 = 0; k4 < cH / 4; ++k4) {
    float4 a[8];
#pragma unroll
    for (int m = 0; m < 8; ++m) a[m] = s4[m * 128 + k4];
    const float* wp = W + (long)(k4 * 4) * cH + col;
    float w0 = wp[0], w1 = wp[cH], w2 = wp[2 * cH], w3 = wp[3 * cH];
#pragma unroll
    for (int m = 0; m < 8; ++m)
      acc[m] += a[m].x * w0 + a[m].y * w1 + a[m].z * w2 + a[m].w * w3;
  }
#pragma unroll
  for (int m = 0; m < 8; ++m) q[(long)(row0 + m) * cH + col] = acc[m];
}

// ---------------- causal attention: scores + softmax + context ----------------
__global__ void k_attn(const float* __restrict__ q, const float* __restrict__ hse,
                       float* __restrict__ c) {
  __shared__ float qs[cH];
  __shared__ float part[256];
  __shared__ float aw[cN];
  int bn = blockIdx.x;
  int b = bn >> 6, n = bn & 63;
  int t = threadIdx.x;
  qs[t] = q[(long)bn * cH + t];
  qs[t + 256] = q[(long)bn * cH + t + 256];
  __syncthreads();
  int k = t & 63;
  int p = t >> 6;  // 4 partials per key
  const float* hrow = hse + ((long)b * cNP1 + 1 + k) * cH + p * 128;
  float s = 0.f;
#pragma unroll 8
  for (int j = 0; j < 128; ++j) s += qs[p * 128 + j] * hrow[j];
  part[t] = s;
  __syncthreads();
  if (t < 64) {
    float sc = part[t] + part[t + 64] + part[t + 128] + part[t + 192];
    if (t > n) sc = -1e30f;  // ref adds log(1e-45) ~ -103.6 -> exp underflows to 0
    float m = sc;
#pragma unroll
    for (int off = 32; off; off >>= 1) m = fmaxf(m, __shfl_xor(m, off));
    float e = __expf(sc - m);
    float sum = e;
#pragma unroll
    for (int off = 32; off; off >>= 1) sum += __shfl_xor(sum, off);
    aw[t] = e / sum;
  }
  __syncthreads();
  float c0 = 0.f, c1 = 0.f;
  for (int kk = 0; kk < cN; ++kk) {
    float a = aw[kk];
    const float* hr = hse + ((long)b * cNP1 + 1 + kk) * cH;
    c0 += a * hr[t];
    c1 += a * hr[t + 256];
  }
  c[(long)bn * cH + t] = c0;
  c[(long)bn * cH + t + 256] = c1;
}

// ---------------- out partials: pko[kp][bn][col] over k-half (c half / hs half) ----------------
// grid (2 col-groups, 256 row-groups, 2 kp); block 256
__global__ void k_outp(const float* __restrict__ c, const float* __restrict__ hse,
                       const float* __restrict__ W, float* __restrict__ pko) {
  __shared__ float s[8 * cH];                      // 16 KB (half of concat per kp)
  int cg = blockIdx.x;
  int row0 = blockIdx.y * 8;
  int kp = blockIdx.z;
  int t = threadIdx.x;
  float4* s4 = (float4*)s;
#pragma unroll
  for (int i = t; i < 8 * 128; i += 256) {
    int m = i >> 7, k4 = i & 127;
    int bn = row0 + m;
    int b = bn >> 6, n = bn & 63;
    const float4* src = (kp == 0) ? (const float4*)(c + (long)bn * cH)
                                  : (const float4*)(hse + ((long)b * cNP1 + 1 + n) * cH);
    s4[m * 128 + k4] = src[k4];
  }
  __syncthreads();
  int col = cg * 256 + t;
  float acc[8] = {0, 0, 0, 0, 0, 0, 0, 0};
#pragma unroll 2
  for (int k4 = 0; k4 < 128; ++k4) {
    float4 a[8];
#pragma unroll
    for (int m = 0; m < 8; ++m) a[m] = s4[m * 128 + k4];
    const float* wp = W + (long)(kp * cH + k4 * 4) * cH + col;
    float w0 = wp[0], w1 = wp[cH], w2 = wp[2 * cH], w3 = wp[3 * cH];
#pragma unroll
    for (int m = 0; m < 8; ++m)
      acc[m] += a[m].x * w0 + a[m].y * w1 + a[m].z * w2 + a[m].w * w3;
  }
#pragma unroll
  for (int m = 0; m < 8; ++m)
    pko[((long)kp * cBN + row0 + m) * cH + col] = acc[m];
}

// ---------------- out = tanh(p0 + p1 + bias) ----------------
__global__ void k_outr(const float* __restrict__ pko, const float* __restrict__ bias,
                       float* __restrict__ out) {
  int bn = blockIdx.x, col = threadIdx.x;  // 512 threads
  long i = (long)bn * cH + col;
  out[i] = tanhf(pko[i] + pko[(long)cBN * cH + i] + bias[col]);
}

extern "C" void kernel_launch(void* const* d_in, const int* in_sizes, int n_in,
                              void* d_out, int out_size, void* d_ws, size_t ws_size,
                              hipStream_t stream) {
  const int* sents = (const int*)d_in[0];
  const int* titles = (const int*)d_in[1];
  const float* emb = (const float*)d_in[2];
  const float* Wt = (const float*)d_in[3];
  const float* bt = (const float*)d_in[4];
  const float* W_ih = (const float*)d_in[5];
  const float* W_hh = (const float*)d_in[6];
  const float* b_ih = (const float*)d_in[7];
  const float* b_hh = (const float*)d_in[8];
  const float* W_att_in = (const float*)d_in[9];
  const float* W_att_out = (const float*)d_in[10];
  const float* b_att_out = (const float*)d_in[11];
  float* out = (float*)d_out;

  float* ws = (float*)d_ws;
  float* x = ws;                                   // BN*D
  float* tsum = x + (long)cBN * cD;                // B*D
  float* gi = tsum + (long)cB * cD;                // BN*3H (dead after scan)
  float* hse = gi + (long)cBN * cH3;               // B*65*H
  float* q = hse + (long)cB * cNP1 * cH;           // BN*H
  float* c = q + (long)cBN * cH;                   // BN*H
  float* pko = gi;                                 // 2*BN*H partials alias dead gi (8.4 < 12.6 MB)

  k_embed_x<<<cBN, 256, 0, stream>>>(sents, emb, x);
  k_title<<<cB, 256, 0, stream>>>(titles, emb, tsum);
  k_h0<<<(cB * cH) / 256, 256, 0, stream>>>(tsum, Wt, bt, hse);
  k_gi<<<dim3(6, cBN / 8), 256, 0, stream>>>(x, W_ih, b_ih, gi);
  for (int step = 0; step < cN; ++step)
    k_gru_step<<<512, 256, 0, stream>>>(gi, W_hh, b_hh, hse, step);
  k_q<<<dim3(2, cBN / 8), 256, 0, stream>>>(hse, W_att_in, q);
  k_attn<<<cBN, 256, 0, stream>>>(q, hse, c);
  k_outp<<<dim3(2, cBN / 8, 2), 256, 0, stream>>>(c, hse, W_att_out, pko);
  k_outr<<<cBN, 512, 0, stream>>>(pko, b_att_out, out);
}